// Round 1
// baseline (6638.584 us; speedup 1.0000x reference)
//
#include <hip/hip_runtime.h>

#define B_ 64
#define T_ 512
#define D_ 256
#define H_ 1024
#define O_ 256
#define KTOT 1280   // D_ + H_
#define NBLK 256

typedef __bf16 bf16x8 __attribute__((ext_vector_type(8)));
typedef float f32x4 __attribute__((ext_vector_type(4)));

__device__ __forceinline__ unsigned short f2bf(float f) {
    unsigned int u = __builtin_bit_cast(unsigned int, f);
    unsigned int r = (u + 0x7fffu + ((u >> 16) & 1u)) >> 16;
    return (unsigned short)r;
}
__device__ __forceinline__ float sigmoid_f(float x) { return 1.f / (1.f + __expf(-x)); }
__device__ __forceinline__ float tanh_f(float x)    { return 1.f - 2.f / (1.f + __expf(2.f * x)); }

// ---------------- sync region layout (int offsets) ----------------
// cntL: (t*16 + leaf)*32                     [0      .. 262144)
// cntR: 262144 + t*32                        [262144 .. 278528)
// rls : 278528 + (t*16 + i)*32               [278528 .. 540672)
#define SYNC_INTS 540672

__global__ void zero_sync(int* s) { s[blockIdx.x * 256 + threadIdx.x] = 0; }

// Pack [W_ih | W_hh] rows into gate-interleaved bf16 rows p = blk*16 + j*4 + g
// (orig row = g*1024 + (blk*4 + j)); also combined bias, and W_out -> bf16.
__global__ __launch_bounds__(256) void pack_weights(
    const float* __restrict__ Wih, const float* __restrict__ Whh,
    const float* __restrict__ bih, const float* __restrict__ bhh,
    const float* __restrict__ Wout,
    unsigned short* __restrict__ Wp, float* __restrict__ bpk,
    unsigned short* __restrict__ Wo)
{
    int bid = blockIdx.x, tid = threadIdx.x;
    if (bid < 4096) {
        int g = bid & 3, j = (bid >> 2) & 3, hc = (bid >> 4) * 4 + j;
        int row = g * 1024 + hc;
        for (int e = tid; e < KTOT; e += 256) {
            float v = (e < D_) ? Wih[(size_t)row * D_ + e] : Whh[(size_t)row * H_ + (e - D_)];
            Wp[(size_t)bid * KTOT + e] = f2bf(v);
        }
        if (tid == 0) bpk[bid] = bih[row] + bhh[row];
    } else {
        int r = bid - 4096;
        for (int e = tid; e < H_; e += 256)
            Wo[(size_t)r * H_ + e] = f2bf(Wout[(size_t)r * H_ + e]);
    }
}

// x [B,T,D] f32 -> xt [T,B,D] bf16
__global__ __launch_bounds__(256) void x_pack(const float* __restrict__ x,
                                              unsigned short* __restrict__ xt)
{
    int bid = blockIdx.x;            // = b*512 + t
    int b = bid >> 9, t = bid & 511;
    int d = threadIdx.x;
    xt[((size_t)t * B_ + b) * D_ + d] = f2bf(x[(size_t)bid * D_ + d]);
}

__global__ __launch_bounds__(256, 1) void lstm_scan(
    const unsigned short* __restrict__ Wp, const float* __restrict__ bpk,
    const unsigned short* __restrict__ xt, unsigned short* __restrict__ hs,
    int* __restrict__ sync)
{
    const int tid  = threadIdx.x;
    const int wid  = tid >> 6, lane = tid & 63;
    const int n    = lane & 15, kg = lane >> 4;
    const int blk  = blockIdx.x;
    const int gq   = n & 3;
    const int hcol = blk * 4 + (n >> 2);

    // Preload this wave's weight fragments: 40 x bf16x8 = 160 VGPR, reused 512 steps.
    bf16x8 wf[40];
    {
        const bf16x8* wp8 = (const bf16x8*)(Wp + (size_t)(blk * 16 + n) * KTOT + kg * 8);
        #pragma unroll
        for (int kk = 0; kk < 40; ++kk) wf[kk] = wp8[kk * 4];
    }
    const float bias = bpk[blk * 16 + n];

    float cc[4] = {0.f, 0.f, 0.f, 0.f};

    for (int t = 0; t < T_; ++t) {
        f32x4 ac[4];
        f32x4 z = {0.f, 0.f, 0.f, 0.f};
        ac[0] = z; ac[1] = z; ac[2] = z; ac[3] = z;

        // x-part: independent of h, do it before waiting on step t-1.
        {
            const bf16x8* ax = (const bf16x8*)(xt + ((size_t)t * B_ + wid * 16 + n) * D_ + kg * 8);
            #pragma unroll
            for (int kk = 0; kk < 8; ++kk) {
                bf16x8 a = ax[kk * 4];
                ac[kk & 3] = __builtin_amdgcn_mfma_f32_16x16x32_bf16(a, wf[kk], ac[kk & 3], 0, 0, 0);
            }
        }

        if (t > 0) {
            if (tid == 0) {
                while (__hip_atomic_load(sync + (278528 + ((t - 1) * 16 + (blk & 15)) * 32),
                                         __ATOMIC_RELAXED, __HIP_MEMORY_SCOPE_AGENT) == 0) {
                    __builtin_amdgcn_s_sleep(1);
                }
            }
            __syncthreads();
            const bf16x8* ah = (const bf16x8*)(hs + ((size_t)(t - 1) * B_ + wid * 16 + n) * H_ + kg * 8);
            #pragma unroll
            for (int kk = 8; kk < 40; ++kk) {
                bf16x8 a = ah[(kk - 8) * 4];
                ac[kk & 3] = __builtin_amdgcn_mfma_f32_16x16x32_bf16(a, wf[kk], ac[kk & 3], 0, 0, 0);
            }
        }

        f32x4 g4 = (ac[0] + ac[1]) + (ac[2] + ac[3]);

        float hv[4];
        #pragma unroll
        for (int r = 0; r < 4; ++r) {
            float v  = g4[r] + bias;
            float v1 = __shfl_xor(v, 1);
            float v2 = __shfl_xor(v, 2);
            float v3 = __shfl_xor(v, 3);
            float iv = (gq == 0) ? v  : (gq == 1) ? v1 : (gq == 2) ? v2 : v3;
            float fv = (gq == 0) ? v1 : (gq == 1) ? v  : (gq == 2) ? v3 : v2;
            float gv = (gq == 0) ? v2 : (gq == 1) ? v3 : (gq == 2) ? v  : v1;
            float ov = (gq == 0) ? v3 : (gq == 1) ? v2 : (gq == 2) ? v1 : v;
            float is = sigmoid_f(iv), fs = sigmoid_f(fv), gt = tanh_f(gv), os = sigmoid_f(ov);
            float cn = fs * cc[r] + is * gt;
            cc[r] = cn;
            hv[r] = os * tanh_f(cn);
        }

        // Store h (bf16) with device-scope stores (write-through to coherence point).
        if (gq == 0) {
            #pragma unroll
            for (int r = 0; r < 4; ++r) {
                int br = wid * 16 + kg * 4 + r;
                __hip_atomic_store(hs + ((size_t)t * B_ + br) * H_ + hcol, f2bf(hv[r]),
                                   __ATOMIC_RELAXED, __HIP_MEMORY_SCOPE_AGENT);
            }
        }

        __syncthreads();   // drains this block's stores (vmcnt) before arrival
        if (tid == 0) {
            int lf = __hip_atomic_fetch_add(sync + ((t * 16 + (blk >> 4)) * 32), 1,
                                            __ATOMIC_ACQ_REL, __HIP_MEMORY_SCOPE_AGENT);
            if (lf == 15) {
                int rt = __hip_atomic_fetch_add(sync + (262144 + t * 32), 1,
                                                __ATOMIC_ACQ_REL, __HIP_MEMORY_SCOPE_AGENT);
                if (rt == 15) {
                    #pragma unroll
                    for (int i = 0; i < 16; ++i)
                        __hip_atomic_store(sync + (278528 + (t * 16 + i) * 32), 1,
                                           __ATOMIC_RELAXED, __HIP_MEMORY_SCOPE_AGENT);
                }
            }
        }
    }
}

// outputs[b,t,o] = hs[t,b,:] @ W_out[o,:] + b_out[o]
__global__ __launch_bounds__(256) void out_proj(
    const unsigned short* __restrict__ hs, const unsigned short* __restrict__ Wo,
    const float* __restrict__ bout, float* __restrict__ out)
{
    const int tid = threadIdx.x, wid = tid >> 6, lane = tid & 63;
    const int n = lane & 15, kg = lane >> 4;
    const int mb = blockIdx.x >> 2, nb = blockIdx.x & 3;
    const int m0 = mb * 64 + wid * 16;
    const int n0 = nb * 64;
    f32x4 acc[4];
    f32x4 z = {0.f, 0.f, 0.f, 0.f};
    acc[0] = z; acc[1] = z; acc[2] = z; acc[3] = z;
    const bf16x8* ap = (const bf16x8*)(hs + ((size_t)(m0 + n)) * H_ + kg * 8);
    #pragma unroll 2
    for (int kk = 0; kk < 32; ++kk) {
        bf16x8 a = ap[kk * 4];
        #pragma unroll
        for (int nt = 0; nt < 4; ++nt) {
            const bf16x8* bp8 = (const bf16x8*)(Wo + ((size_t)(n0 + nt * 16 + n)) * H_ + kg * 8);
            bf16x8 b = bp8[kk * 4];
            acc[nt] = __builtin_amdgcn_mfma_f32_16x16x32_bf16(a, b, acc[nt], 0, 0, 0);
        }
    }
    #pragma unroll
    for (int nt = 0; nt < 4; ++nt) {
        int col = n0 + nt * 16 + n;
        float bias = bout[col];
        #pragma unroll
        for (int r = 0; r < 4; ++r) {
            int m = m0 + kg * 4 + r;
            int tt = m >> 6, bb = m & 63;
            out[((size_t)bb * T_ + tt) * O_ + col] = acc[nt][r] + bias;
        }
    }
}

extern "C" void kernel_launch(void* const* d_in, const int* in_sizes, int n_in,
                              void* d_out, int out_size, void* d_ws, size_t ws_size,
                              hipStream_t stream)
{
    const float* x    = (const float*)d_in[0];
    const float* Wih  = (const float*)d_in[1];
    const float* Whh  = (const float*)d_in[2];
    const float* bih  = (const float*)d_in[3];
    const float* bhh  = (const float*)d_in[4];
    const float* Wout = (const float*)d_in[5];
    const float* bout = (const float*)d_in[6];
    float* out = (float*)d_out;

    char* ws = (char*)d_ws;
    unsigned short* Wp  = (unsigned short*)ws;  ws += (size_t)4096 * KTOT * 2;   // 10485760
    float*          bpk = (float*)ws;           ws += (size_t)4096 * 4;          // 16384
    unsigned short* Wo  = (unsigned short*)ws;  ws += (size_t)O_ * H_ * 2;       // 524288
    unsigned short* xt  = (unsigned short*)ws;  ws += (size_t)T_ * B_ * D_ * 2;  // 16777216
    unsigned short* hs  = (unsigned short*)ws;  ws += (size_t)T_ * B_ * H_ * 2;  // 67108864
    int*            syn = (int*)ws;             ws += (size_t)SYNC_INTS * 4;     // 2162688

    if (ws_size < (size_t)(ws - (char*)d_ws)) return;  // ~97 MB required

    zero_sync<<<SYNC_INTS / 256, 256, 0, stream>>>(syn);
    pack_weights<<<4096 + 256, 256, 0, stream>>>(Wih, Whh, bih, bhh, Wout, Wp, bpk, Wo);
    x_pack<<<B_ * T_, 256, 0, stream>>>(x, xt);

    {
        const unsigned short* Wpc = Wp;
        const float*          bpc = bpk;
        const unsigned short* xtc = xt;
        unsigned short*       hsv = hs;
        int*                  syv = syn;
        void* args[5] = {(void*)&Wpc, (void*)&bpc, (void*)&xtc, (void*)&hsv, (void*)&syv};
        hipLaunchCooperativeKernel((void*)lstm_scan, dim3(NBLK), dim3(256), args, 0, stream);
    }

    out_proj<<<(T_ * B_ / 64) * 4, 256, 0, stream>>>(hs, Wo, bout, out);
}

// Round 2
// 4242.493 us; speedup vs baseline: 1.5648x; 1.5648x over previous
//
#include <hip/hip_runtime.h>

#define B_ 64
#define T_ 512
#define D_ 256
#define H_ 1024
#define O_ 256
#define KTOT 1280   // D_ + H_
#define NBLK 256

typedef __bf16 bf16x8 __attribute__((ext_vector_type(8)));
typedef float f32x4 __attribute__((ext_vector_type(4)));

__device__ __forceinline__ unsigned short f2bf(float f) {
    unsigned int u = __builtin_bit_cast(unsigned int, f);
    unsigned int r = (u + 0x7fffu + ((u >> 16) & 1u)) >> 16;
    return (unsigned short)r;
}
__device__ __forceinline__ float sigmoid_f(float x) { return 1.f / (1.f + __expf(-x)); }
__device__ __forceinline__ float tanh_f(float x)    { return 1.f - 2.f / (1.f + __expf(2.f * x)); }

// ---------------- sync region layout (int offsets) ----------------
// cntL: (t*16 + leaf)*32                     [0      .. 262144)
// cntR: 262144 + t*32                        [262144 .. 278528)
// rls : 278528 + (t*16 + i)*32               [278528 .. 540672)
#define SYNC_INTS 540672

__global__ void zero_sync(int* s) { s[blockIdx.x * 256 + threadIdx.x] = 0; }

// Pack [W_ih | W_hh] rows into gate-interleaved bf16 rows p = blk*16 + j*4 + g
// (orig row = g*1024 + (blk*4 + j)); also combined bias, and W_out -> bf16.
__global__ __launch_bounds__(256) void pack_weights(
    const float* __restrict__ Wih, const float* __restrict__ Whh,
    const float* __restrict__ bih, const float* __restrict__ bhh,
    const float* __restrict__ Wout,
    unsigned short* __restrict__ Wp, float* __restrict__ bpk,
    unsigned short* __restrict__ Wo)
{
    int bid = blockIdx.x, tid = threadIdx.x;
    if (bid < 4096) {
        int g = bid & 3, j = (bid >> 2) & 3, hc = (bid >> 4) * 4 + j;
        int row = g * 1024 + hc;
        for (int e = tid; e < KTOT; e += 256) {
            float v = (e < D_) ? Wih[(size_t)row * D_ + e] : Whh[(size_t)row * H_ + (e - D_)];
            Wp[(size_t)bid * KTOT + e] = f2bf(v);
        }
        if (tid == 0) bpk[bid] = bih[row] + bhh[row];
    } else {
        int r = bid - 4096;
        for (int e = tid; e < H_; e += 256)
            Wo[(size_t)r * H_ + e] = f2bf(Wout[(size_t)r * H_ + e]);
    }
}

// x [B,T,D] f32 -> xt [T,B,D] bf16
__global__ __launch_bounds__(256) void x_pack(const float* __restrict__ x,
                                              unsigned short* __restrict__ xt)
{
    int bid = blockIdx.x;            // = b*512 + t
    int b = bid >> 9, t = bid & 511;
    int d = threadIdx.x;
    xt[((size_t)t * B_ + b) * D_ + d] = f2bf(x[(size_t)bid * D_ + d]);
}

__global__ __launch_bounds__(256, 1) void lstm_scan(
    const unsigned short* __restrict__ Wp, const float* __restrict__ bpk,
    const unsigned short* __restrict__ xt, unsigned short* __restrict__ hs,
    int* __restrict__ sync)
{
    const int tid  = threadIdx.x;
    const int wid  = tid >> 6, lane = tid & 63;
    const int n    = lane & 15, kg = lane >> 4;
    const int blk  = blockIdx.x;
    const int gq   = n & 3;
    const int hcol = blk * 4 + (n >> 2);

    // Preload this wave's weight fragments: 40 x bf16x8 = 160 VGPR, reused 512 steps.
    bf16x8 wf[40];
    {
        const bf16x8* wp8 = (const bf16x8*)(Wp + (size_t)(blk * 16 + n) * KTOT + kg * 8);
        #pragma unroll
        for (int kk = 0; kk < 40; ++kk) wf[kk] = wp8[kk * 4];
    }
    // Pin the weight fragments in registers: opaque redefinition prevents the
    // compiler from sinking/rematerializing the loads inside the t-loop.
    #pragma unroll
    for (int kk = 0; kk < 40; ++kk) asm volatile("" : "+v"(wf[kk]));

    const float bias = bpk[blk * 16 + n];

    float cc[4] = {0.f, 0.f, 0.f, 0.f};

    for (int t = 0; t < T_; ++t) {
        f32x4 ac[4];
        f32x4 z = {0.f, 0.f, 0.f, 0.f};
        ac[0] = z; ac[1] = z; ac[2] = z; ac[3] = z;

        // x-part: independent of h, do it before waiting on step t-1.
        {
            const bf16x8* ax = (const bf16x8*)(xt + ((size_t)t * B_ + wid * 16 + n) * D_ + kg * 8);
            #pragma unroll
            for (int kk = 0; kk < 8; ++kk) {
                bf16x8 a = ax[kk * 4];
                ac[kk & 3] = __builtin_amdgcn_mfma_f32_16x16x32_bf16(a, wf[kk], ac[kk & 3], 0, 0, 0);
            }
        }

        if (t > 0) {
            if (tid == 0) {
                while (__hip_atomic_load(sync + (278528 + ((t - 1) * 16 + (blk & 15)) * 32),
                                         __ATOMIC_RELAXED, __HIP_MEMORY_SCOPE_AGENT) == 0) {
                    __builtin_amdgcn_s_sleep(1);
                }
            }
            __syncthreads();
            const bf16x8* ah = (const bf16x8*)(hs + ((size_t)(t - 1) * B_ + wid * 16 + n) * H_ + kg * 8);
            #pragma unroll
            for (int kk = 8; kk < 40; ++kk) {
                bf16x8 a = ah[(kk - 8) * 4];
                ac[kk & 3] = __builtin_amdgcn_mfma_f32_16x16x32_bf16(a, wf[kk], ac[kk & 3], 0, 0, 0);
            }
        }

        f32x4 g4 = (ac[0] + ac[1]) + (ac[2] + ac[3]);

        float hv[4];
        #pragma unroll
        for (int r = 0; r < 4; ++r) {
            float v  = g4[r] + bias;
            float v1 = __shfl_xor(v, 1);
            float v2 = __shfl_xor(v, 2);
            float v3 = __shfl_xor(v, 3);
            float iv = (gq == 0) ? v  : (gq == 1) ? v1 : (gq == 2) ? v2 : v3;
            float fv = (gq == 0) ? v1 : (gq == 1) ? v  : (gq == 2) ? v3 : v2;
            float gv = (gq == 0) ? v2 : (gq == 1) ? v3 : (gq == 2) ? v  : v1;
            float ov = (gq == 0) ? v3 : (gq == 1) ? v2 : (gq == 2) ? v1 : v;
            float is = sigmoid_f(iv), fs = sigmoid_f(fv), gt = tanh_f(gv), os = sigmoid_f(ov);
            float cn = fs * cc[r] + is * gt;
            cc[r] = cn;
            hv[r] = os * tanh_f(cn);
        }

        // Store h (bf16) with device-scope stores (write-through to coherence point).
        if (gq == 0) {
            #pragma unroll
            for (int r = 0; r < 4; ++r) {
                int br = wid * 16 + kg * 4 + r;
                __hip_atomic_store(hs + ((size_t)t * B_ + br) * H_ + hcol, f2bf(hv[r]),
                                   __ATOMIC_RELAXED, __HIP_MEMORY_SCOPE_AGENT);
            }
        }

        // __syncthreads emits s_waitcnt vmcnt(0) per wave before s_barrier:
        // all h stores of this block have reached the coherence point before
        // tid 0 publishes arrival. RELAXED atomics only — agent-scope acq_rel
        // would emit buffer_wbl2/buffer_inv (whole-L2 maintenance) per call.
        __syncthreads();
        if (tid == 0) {
            int lf = __hip_atomic_fetch_add(sync + ((t * 16 + (blk >> 4)) * 32), 1,
                                            __ATOMIC_RELAXED, __HIP_MEMORY_SCOPE_AGENT);
            if (lf == 15) {
                int rt = __hip_atomic_fetch_add(sync + (262144 + t * 32), 1,
                                                __ATOMIC_RELAXED, __HIP_MEMORY_SCOPE_AGENT);
                if (rt == 15) {
                    #pragma unroll
                    for (int i = 0; i < 16; ++i)
                        __hip_atomic_store(sync + (278528 + (t * 16 + i) * 32), 1,
                                           __ATOMIC_RELAXED, __HIP_MEMORY_SCOPE_AGENT);
                }
            }
        }
    }
}

// outputs[b,t,o] = hs[t,b,:] @ W_out[o,:] + b_out[o]
__global__ __launch_bounds__(256) void out_proj(
    const unsigned short* __restrict__ hs, const unsigned short* __restrict__ Wo,
    const float* __restrict__ bout, float* __restrict__ out)
{
    const int tid = threadIdx.x, wid = tid >> 6, lane = tid & 63;
    const int n = lane & 15, kg = lane >> 4;
    const int mb = blockIdx.x >> 2, nb = blockIdx.x & 3;
    const int m0 = mb * 64 + wid * 16;
    const int n0 = nb * 64;
    f32x4 acc[4];
    f32x4 z = {0.f, 0.f, 0.f, 0.f};
    acc[0] = z; acc[1] = z; acc[2] = z; acc[3] = z;
    const bf16x8* ap = (const bf16x8*)(hs + ((size_t)(m0 + n)) * H_ + kg * 8);
    #pragma unroll 2
    for (int kk = 0; kk < 32; ++kk) {
        bf16x8 a = ap[kk * 4];
        #pragma unroll
        for (int nt = 0; nt < 4; ++nt) {
            const bf16x8* bp8 = (const bf16x8*)(Wo + ((size_t)(n0 + nt * 16 + n)) * H_ + kg * 8);
            bf16x8 b = bp8[kk * 4];
            acc[nt] = __builtin_amdgcn_mfma_f32_16x16x32_bf16(a, b, acc[nt], 0, 0, 0);
        }
    }
    #pragma unroll
    for (int nt = 0; nt < 4; ++nt) {
        int col = n0 + nt * 16 + n;
        float bias = bout[col];
        #pragma unroll
        for (int r = 0; r < 4; ++r) {
            int m = m0 + kg * 4 + r;
            int tt = m >> 6, bb = m & 63;
            out[((size_t)bb * T_ + tt) * O_ + col] = acc[nt][r] + bias;
        }
    }
}

extern "C" void kernel_launch(void* const* d_in, const int* in_sizes, int n_in,
                              void* d_out, int out_size, void* d_ws, size_t ws_size,
                              hipStream_t stream)
{
    const float* x    = (const float*)d_in[0];
    const float* Wih  = (const float*)d_in[1];
    const float* Whh  = (const float*)d_in[2];
    const float* bih  = (const float*)d_in[3];
    const float* bhh  = (const float*)d_in[4];
    const float* Wout = (const float*)d_in[5];
    const float* bout = (const float*)d_in[6];
    float* out = (float*)d_out;

    char* ws = (char*)d_ws;
    unsigned short* Wp  = (unsigned short*)ws;  ws += (size_t)4096 * KTOT * 2;   // 10485760
    float*          bpk = (float*)ws;           ws += (size_t)4096 * 4;          // 16384
    unsigned short* Wo  = (unsigned short*)ws;  ws += (size_t)O_ * H_ * 2;       // 524288
    unsigned short* xt  = (unsigned short*)ws;  ws += (size_t)T_ * B_ * D_ * 2;  // 16777216
    unsigned short* hs  = (unsigned short*)ws;  ws += (size_t)T_ * B_ * H_ * 2;  // 67108864
    int*            syn = (int*)ws;             ws += (size_t)SYNC_INTS * 4;     // 2162688

    if (ws_size < (size_t)(ws - (char*)d_ws)) return;  // ~97 MB required

    zero_sync<<<SYNC_INTS / 256, 256, 0, stream>>>(syn);
    pack_weights<<<4096 + 256, 256, 0, stream>>>(Wih, Whh, bih, bhh, Wout, Wp, bpk, Wo);
    x_pack<<<B_ * T_, 256, 0, stream>>>(x, xt);

    {
        const unsigned short* Wpc = Wp;
        const float*          bpc = bpk;
        const unsigned short* xtc = xt;
        unsigned short*       hsv = hs;
        int*                  syv = syn;
        void* args[5] = {(void*)&Wpc, (void*)&bpc, (void*)&xtc, (void*)&hsv, (void*)&syv};
        hipLaunchCooperativeKernel((void*)lstm_scan, dim3(NBLK), dim3(256), args, 0, stream);
    }

    out_proj<<<(T_ * B_ / 64) * 4, 256, 0, stream>>>(hs, Wo, bout, out);
}